// Round 23
// baseline (421.144 us; speedup 1.0000x reference)
//
#include <hip/hip_runtime.h>
#include <math.h>

#define BB 8
#define NN 2048
#define FIN 128
#define FOUT 64
#define TI 16
#define TJ 256
#define TJP (TJ + 8)
#define NTILE (NN / TJ)
#define PREP 4

typedef short bf16x8 __attribute__((ext_vector_type(8)));
typedef float f32x4 __attribute__((ext_vector_type(4)));

__device__ __forceinline__ float exp_tanh(float z) {
    float zc = fminf(fmaxf(z, -15.f), 15.f);
    float u = __expf(zc + zc);
    float tn = (u - 1.f) * __builtin_amdgcn_rcpf(u + 1.f);
    return __expf(tn);
}

__device__ __forceinline__ unsigned short f2bf(float x) {
    union { float f; unsigned u; } v; v.f = x;
    unsigned r = v.u + 0x7FFF + ((v.u >> 16) & 1);
    return (unsigned short)(r >> 16);
}

// K1: verbatim R20 (panel-major ht[b][n/32][c][n%32])
__global__ __launch_bounds__(256, 2) void gat_k1(const float* __restrict__ x,
                                                 const float* __restrict__ W,
                                                 const float* __restrict__ a,
                                                 unsigned short* __restrict__ ht,
                                                 float* __restrict__ f1,
                                                 float* __restrict__ f2) {
    __shared__ __attribute__((aligned(16))) float Wl[FIN][FOUT];
    __shared__ __attribute__((aligned(16))) float xs[16][FIN];
    int t = threadIdx.x;

    const float4* W4 = (const float4*)W;
    float4* Wl4 = (float4*)&Wl[0][0];
#pragma unroll
    for (int kk = 0; kk < 8; ++kk) Wl4[t + 256 * kk] = W4[t + 256 * kk];

    size_t row0 = (size_t)blockIdx.x * 16;
    const float4* x4 = (const float4*)(x + row0 * FIN);
    float4* xs4 = (float4*)&xs[0][0];
#pragma unroll
    for (int kk = 0; kk < 2; ++kk) xs4[t + 256 * kk] = x4[t + 256 * kk];
    __syncthreads();

    int c = t & 63;
    int rq = t >> 6;
    float acc[4] = {0.f, 0.f, 0.f, 0.f};
#pragma unroll 8
    for (int k = 0; k < FIN; ++k) {
        float wv = Wl[k][c];
        acc[0] = fmaf(xs[rq][k], wv, acc[0]);
        acc[1] = fmaf(xs[rq + 4][k], wv, acc[1]);
        acc[2] = fmaf(xs[rq + 8][k], wv, acc[2]);
        acc[3] = fmaf(xs[rq + 12][k], wv, acc[3]);
    }
    float a1c = a[c], a2c = a[FOUT + c];
#pragma unroll
    for (int m = 0; m < 4; ++m) {
        size_t bn = row0 + rq + 4 * m;
        int b = (int)(bn >> 11);
        int n = (int)(bn & 2047);
        ht[((size_t)b * (NN / 32) + (n >> 5)) * (FOUT * 32) + c * 32 + (n & 31)] =
            f2bf(acc[m]);
        float p1 = acc[m] * a1c;
        float p2 = acc[m] * a2c;
#pragma unroll
        for (int off = 32; off > 0; off >>= 1) {
            p1 += __shfl_down(p1, off, 64);
            p2 += __shfl_down(p2, off, 64);
        }
        if (c == 0) { f1[bn] = p1; f2[bn] = p2; }
    }
}

// K2f: byte-identical to R20 (216.3us best).
__global__ __launch_bounds__(256) void gat_k2f(const int* __restrict__ adj,
                                               const unsigned short* __restrict__ ht,
                                               const float* __restrict__ f1,
                                               const float* __restrict__ f2,
                                               float* __restrict__ out) {
    __shared__ __attribute__((aligned(16))) unsigned short pb[TI][TJP];
    __shared__ __attribute__((aligned(16))) float f2s[TJ];
    __shared__ float f1s[TI];
    __shared__ float rsw[TI];

    int t = threadIdx.x;
    int i0 = blockIdx.x * TI;
    int b = blockIdx.y;

    int lane = t & 63;
    int w = t >> 6;
    int mrow = lane & 15;
    int quad = lane >> 4;
    int j4 = t & 63;

    if (t < TI) f1s[t] = f1[(size_t)b * NN + i0 + t];
    __syncthreads();

    float f1r[4];
    float ps[4];
#pragma unroll
    for (int m = 0; m < 4; ++m) {
        f1r[m] = f1s[w + 4 * m];
        ps[m] = 0.f;
    }
    f32x4 acc = {0.f, 0.f, 0.f, 0.f};

    const int* adjrow = adj + (((size_t)b * NN + i0) * NN) + 4 * j4;
    const unsigned short* htb =
        ht + (size_t)b * (NN / 32) * (FOUT * 32)
           + (size_t)(w * 16 + mrow) * 32 + 8 * quad;

    for (int jt = 0; jt < NTILE; ++jt) {
        int j0 = jt * TJ;

        int4 avreg[4];
#pragma unroll
        for (int m = 0; m < 4; ++m)
            avreg[m] = *(const int4*)(adjrow + (size_t)(w + 4 * m) * NN + j0);

        f2s[t] = f2[(size_t)b * NN + j0 + t];
        __syncthreads();

        float4 fv = ((const float4*)f2s)[j4];
#pragma unroll
        for (int m = 0; m < 4; ++m) {
            int4 av = avreg[m];
            float f1i = f1r[m];
            float4 p;
            p.x = (av.x > 0) ? exp_tanh(f1i + fv.x) : 0.f;
            p.y = (av.y > 0) ? exp_tanh(f1i + fv.y) : 0.f;
            p.z = (av.z > 0) ? exp_tanh(f1i + fv.z) : 0.f;
            p.w = (av.w > 0) ? exp_tanh(f1i + fv.w) : 0.f;
            ps[m] += p.x + p.y + p.z + p.w;
            ushort4 pk;
            pk.x = f2bf(p.x); pk.y = f2bf(p.y);
            pk.z = f2bf(p.z); pk.w = f2bf(p.w);
            *(ushort4*)&pb[w + 4 * m][4 * j4] = pk;
        }
        __syncthreads();

        const unsigned short* prow = &pb[mrow][8 * quad];
        const unsigned short* hpan = htb + (size_t)(j0 >> 5) * (FOUT * 32);
#pragma unroll
        for (int ch = 0; ch < TJ / 32; ++ch) {
            bf16x8 af = *(const bf16x8*)(prow + 32 * ch);
            bf16x8 bf = *(const bf16x8*)(hpan + (size_t)ch * (FOUT * 32));
            acc = __builtin_amdgcn_mfma_f32_16x16x32_bf16(af, bf, acc, 0, 0, 0);
        }
    }

#pragma unroll
    for (int m = 0; m < 4; ++m) {
        float s = ps[m];
#pragma unroll
        for (int off = 32; off > 0; off >>= 1) s += __shfl_down(s, off, 64);
        if (lane == 0) rsw[w + 4 * m] = s;
    }
    __syncthreads();

    float* op = out + ((size_t)b * NN + i0) * FOUT + w * 16 + mrow;
#pragma unroll
    for (int u = 0; u < 4; ++u) {
        int row = quad * 4 + u;
        float rinv = __builtin_amdgcn_rcpf(rsw[row]);
        float sx = acc[u] * rinv;
        op[(size_t)row * FOUT] = (sx > 0.f) ? sx : expm1f(sx);
    }
}

// P3 (R23): P2 + ht B-LOADS (batched, sink-consumed). No af/MFMA.
// Isolates the ht-load side of the PV ghost.
__global__ __launch_bounds__(256) void gat_p3(const int* __restrict__ adj,
                                              const unsigned short* __restrict__ ht,
                                              const float* __restrict__ f1,
                                              const float* __restrict__ f2,
                                              float* __restrict__ scr) {
    __shared__ __attribute__((aligned(16))) unsigned short pb[TI][TJP];
    __shared__ __attribute__((aligned(16))) float f2s[TJ];
    __shared__ float f1s[TI];
    int t = threadIdx.x;
    int i0 = blockIdx.x * TI;
    int b = blockIdx.y;
    int lane = t & 63;
    int w = t >> 6;
    int mrow = lane & 15;
    int quad = lane >> 4;
    int j4 = t & 63;

    if (t < TI) f1s[t] = f1[(size_t)b * NN + i0 + t];
    __syncthreads();
    float f1r[4];
    float ps[4];
#pragma unroll
    for (int m = 0; m < 4; ++m) { f1r[m] = f1s[w + 4 * m]; ps[m] = 0.f; }

    const int* adjrow = adj + (((size_t)b * NN + i0) * NN) + 4 * j4;
    const unsigned short* htb =
        ht + (size_t)b * (NN / 32) * (FOUT * 32)
           + (size_t)(w * 16 + mrow) * 32 + 8 * quad;
    float sink = 0.f;
    int isink = 0;

#pragma unroll 1
    for (int rep = 0; rep < PREP; ++rep) {
#pragma unroll 1
        for (int jt = 0; jt < NTILE; ++jt) {
            int j0 = (((jt + rep) & (NTILE - 1))) * TJ;

            int4 avreg[4];
#pragma unroll
            for (int m = 0; m < 4; ++m)
                avreg[m] = *(const int4*)(adjrow + (size_t)(w + 4 * m) * NN + j0);

            const unsigned short* hpan = htb + (size_t)(j0 >> 5) * (FOUT * 32);
            bf16x8 bfreg[8];
#pragma unroll
            for (int ch = 0; ch < 8; ++ch)
                bfreg[ch] = *(const bf16x8*)(hpan + (size_t)ch * (FOUT * 32));
            __builtin_amdgcn_sched_barrier(0);

            f2s[t] = f2[(size_t)b * NN + j0 + t];
            __syncthreads();

            float4 fv = ((const float4*)f2s)[j4];
#pragma unroll
            for (int m = 0; m < 4; ++m) {
                int4 av = avreg[m];
                float f1i = f1r[m];
                float4 p;
                p.x = (av.x > 0) ? exp_tanh(f1i + fv.x) : 0.f;
                p.y = (av.y > 0) ? exp_tanh(f1i + fv.y) : 0.f;
                p.z = (av.z > 0) ? exp_tanh(f1i + fv.z) : 0.f;
                p.w = (av.w > 0) ? exp_tanh(f1i + fv.w) : 0.f;
                ps[m] += p.x + p.y + p.z + p.w;
                ushort4 pk;
                pk.x = f2bf(p.x); pk.y = f2bf(p.y);
                pk.z = f2bf(p.z); pk.w = f2bf(p.w);
                *(ushort4*)&pb[w + 4 * m][4 * j4] = pk;
            }
            __syncthreads();

            // consume the ht loads (keeps them live; no MFMA, no af reads)
#pragma unroll
            for (int ch = 0; ch < 8; ++ch)
                isink += bfreg[ch][0] + bfreg[ch][3] + bfreg[ch][7];
            sink += (float)pb[t >> 4][(t & 15) * 16];
        }
    }
#pragma unroll
    for (int m = 0; m < 4; ++m) sink += ps[m];
    scr[((size_t)b * (NN / TI) + blockIdx.x) * 256 + t] = sink + (float)isink;
}

// P4 (R23): P2 + af LDS-READS + FULL MFMA CHAIN (B-frag = register const).
// No ht loads. Isolates the LDS-af/MFMA side of the PV ghost.
__global__ __launch_bounds__(256) void gat_p4(const int* __restrict__ adj,
                                              const float* __restrict__ f1,
                                              const float* __restrict__ f2,
                                              float* __restrict__ scr) {
    __shared__ __attribute__((aligned(16))) unsigned short pb[TI][TJP];
    __shared__ __attribute__((aligned(16))) float f2s[TJ];
    __shared__ float f1s[TI];
    int t = threadIdx.x;
    int i0 = blockIdx.x * TI;
    int b = blockIdx.y;
    int lane = t & 63;
    int w = t >> 6;
    int mrow = lane & 15;
    int quad = lane >> 4;
    int j4 = t & 63;

    if (t < TI) f1s[t] = f1[(size_t)b * NN + i0 + t];
    __syncthreads();
    float f1r[4];
    float ps[4];
#pragma unroll
    for (int m = 0; m < 4; ++m) { f1r[m] = f1s[w + 4 * m]; ps[m] = 0.f; }

    // register-constant B fragment (data-dependent so not constant-folded)
    bf16x8 bfconst;
    unsigned short bc = f2bf(f1r[0] + 1.f);
#pragma unroll
    for (int e = 0; e < 8; ++e) bfconst[e] = (short)bc;

    f32x4 acc = {0.f, 0.f, 0.f, 0.f};
    const int* adjrow = adj + (((size_t)b * NN + i0) * NN) + 4 * j4;

#pragma unroll 1
    for (int rep = 0; rep < PREP; ++rep) {
#pragma unroll 1
        for (int jt = 0; jt < NTILE; ++jt) {
            int j0 = (((jt + rep) & (NTILE - 1))) * TJ;

            int4 avreg[4];
#pragma unroll
            for (int m = 0; m < 4; ++m)
                avreg[m] = *(const int4*)(adjrow + (size_t)(w + 4 * m) * NN + j0);

            f2s[t] = f2[(size_t)b * NN + j0 + t];
            __syncthreads();

            float4 fv = ((const float4*)f2s)[j4];
#pragma unroll
            for (int m = 0; m < 4; ++m) {
                int4 av = avreg[m];
                float f1i = f1r[m];
                float4 p;
                p.x = (av.x > 0) ? exp_tanh(f1i + fv.x) : 0.f;
                p.y = (av.y > 0) ? exp_tanh(f1i + fv.y) : 0.f;
                p.z = (av.z > 0) ? exp_tanh(f1i + fv.z) : 0.f;
                p.w = (av.w > 0) ? exp_tanh(f1i + fv.w) : 0.f;
                ps[m] += p.x + p.y + p.z + p.w;
                ushort4 pk;
                pk.x = f2bf(p.x); pk.y = f2bf(p.y);
                pk.z = f2bf(p.z); pk.w = f2bf(p.w);
                *(ushort4*)&pb[w + 4 * m][4 * j4] = pk;
            }
            __syncthreads();

            // full PV shape: af LDS reads + 8 chained MFMAs (const B)
            const unsigned short* prow = &pb[mrow][8 * quad];
#pragma unroll
            for (int ch = 0; ch < 8; ++ch) {
                bf16x8 af = *(const bf16x8*)(prow + 32 * ch);
                acc = __builtin_amdgcn_mfma_f32_16x16x32_bf16(af, bfconst, acc, 0, 0, 0);
            }
        }
    }
    float sink = acc[0] + acc[1] + acc[2] + acc[3];
#pragma unroll
    for (int m = 0; m < 4; ++m) sink += ps[m];
    scr[((size_t)b * (NN / TI) + blockIdx.x) * 256 + t] = sink;
}

extern "C" void kernel_launch(void* const* d_in, const int* in_sizes, int n_in,
                              void* d_out, int out_size, void* d_ws, size_t ws_size,
                              hipStream_t stream) {
    const float* x   = (const float*)d_in[0];
    const int*   adj = (const int*)d_in[1];
    const float* W   = (const float*)d_in[2];
    const float* a   = (const float*)d_in[3];
    float* out = (float*)d_out;

    unsigned short* ht = (unsigned short*)d_ws;          // 2.1 MB, panel-major
    float* f1   = (float*)(ht + (size_t)BB * FOUT * NN); // B*N
    float* f2   = f1 + (size_t)BB * NN;                  // B*N
    float* scr3 = f2 + (size_t)BB * NN;                  // 1 MB probe sink
    float* scr4 = scr3 + (size_t)BB * (NN / TI) * 256;   // 1 MB probe sink

    gat_k1<<<dim3(BB * NN / 16), dim3(256), 0, stream>>>(x, W, a, ht, f1, f2);
    gat_k2f<<<dim3(NN / TI, BB), dim3(256), 0, stream>>>(adj, ht, f1, f2, out);
    // R23 bisection probes (sacrificial round; out already final)
    gat_p3<<<dim3(NN / TI, BB), dim3(256), 0, stream>>>(adj, ht, f1, f2, scr3);
    gat_p4<<<dim3(NN / TI, BB), dim3(256), 0, stream>>>(adj, f1, f2, scr4);
}

// Round 24
// 218.283 us; speedup vs baseline: 1.9294x; 1.9294x over previous
//
#include <hip/hip_runtime.h>
#include <math.h>

#define BB 8
#define NN 2048
#define FIN 128
#define FOUT 64
#define TI 16
#define TJ 256
#define TJP (TJ + 8)
#define NTILE (NN / TJ)

typedef short bf16x8 __attribute__((ext_vector_type(8)));
typedef float f32x4 __attribute__((ext_vector_type(4)));

__device__ __forceinline__ float exp_tanh(float z) {
    float zc = fminf(fmaxf(z, -15.f), 15.f);
    float u = __expf(zc + zc);
    float tn = (u - 1.f) * __builtin_amdgcn_rcpf(u + 1.f);
    return __expf(tn);
}

__device__ __forceinline__ unsigned short f2bf(float x) {
    union { float f; unsigned u; } v; v.f = x;
    unsigned r = v.u + 0x7FFF + ((v.u >> 16) & 1);
    return (unsigned short)(r >> 16);
}

// K1: verbatim R20 (panel-major ht[b][n/32][c][n%32])
__global__ __launch_bounds__(256, 2) void gat_k1(const float* __restrict__ x,
                                                 const float* __restrict__ W,
                                                 const float* __restrict__ a,
                                                 unsigned short* __restrict__ ht,
                                                 float* __restrict__ f1,
                                                 float* __restrict__ f2) {
    __shared__ __attribute__((aligned(16))) float Wl[FIN][FOUT];
    __shared__ __attribute__((aligned(16))) float xs[16][FIN];
    int t = threadIdx.x;

    const float4* W4 = (const float4*)W;
    float4* Wl4 = (float4*)&Wl[0][0];
#pragma unroll
    for (int kk = 0; kk < 8; ++kk) Wl4[t + 256 * kk] = W4[t + 256 * kk];

    size_t row0 = (size_t)blockIdx.x * 16;
    const float4* x4 = (const float4*)(x + row0 * FIN);
    float4* xs4 = (float4*)&xs[0][0];
#pragma unroll
    for (int kk = 0; kk < 2; ++kk) xs4[t + 256 * kk] = x4[t + 256 * kk];
    __syncthreads();

    int c = t & 63;
    int rq = t >> 6;
    float acc[4] = {0.f, 0.f, 0.f, 0.f};
#pragma unroll 8
    for (int k = 0; k < FIN; ++k) {
        float wv = Wl[k][c];
        acc[0] = fmaf(xs[rq][k], wv, acc[0]);
        acc[1] = fmaf(xs[rq + 4][k], wv, acc[1]);
        acc[2] = fmaf(xs[rq + 8][k], wv, acc[2]);
        acc[3] = fmaf(xs[rq + 12][k], wv, acc[3]);
    }
    float a1c = a[c], a2c = a[FOUT + c];
#pragma unroll
    for (int m = 0; m < 4; ++m) {
        size_t bn = row0 + rq + 4 * m;
        int b = (int)(bn >> 11);
        int n = (int)(bn & 2047);
        ht[((size_t)b * (NN / 32) + (n >> 5)) * (FOUT * 32) + c * 32 + (n & 31)] =
            f2bf(acc[m]);
        float p1 = acc[m] * a1c;
        float p2 = acc[m] * a2c;
#pragma unroll
        for (int off = 32; off > 0; off >>= 1) {
            p1 += __shfl_down(p1, off, 64);
            p2 += __shfl_down(p2, off, 64);
        }
        if (c == 0) { f1[bn] = p1; f2[bn] = p2; }
    }
}

// K2f R24: ONE barrier per tile + post-barrier load issue + pb double-buffer.
// R23 bisection: every phase isolated is cheap (P1 skel 18.2/rep, p-phase
// +5, ht-loads +8.3, af+MFMA ~0) yet assembled k2f = 110+ warm. The cost
// is the ASSEMBLY: per-tile [vm-drain -> p-phase -> barrier -> PV ->
// barrier] lockstep. This structure is the untested sync cell: loads for
// tile jt+1 issue AFTER barrier(jt), consumed at p-phase(jt+1) -- the
// issue->consume window contains PV(jt) and crosses NO barrier, so no
// vmcnt(0) drain ever catches an in-flight load (fixes R17's failure
// mode structurally). pb[2] double-buffer makes one barrier/tile safe:
// write(jt+2)->pb[jt&1] is ordered after barrier(jt+1) which follows
// every wave's PV(jt) read of pb[jt&1] (program order: PV(jt) precedes
// p-phase(jt+1) precedes barrier(jt+1)). f2 read direct as float4
// (16B/lane coalesced, L3-warm) -- f2s stage deleted. Single avreg set:
// consume(jt) precedes re-issue(jt+1) per wave. Math order identical to
// R20 -> absmax exactly 0.001953125.
__global__ __launch_bounds__(256) void gat_k2f(const int* __restrict__ adj,
                                               const unsigned short* __restrict__ ht,
                                               const float* __restrict__ f1,
                                               const float* __restrict__ f2,
                                               float* __restrict__ out) {
    __shared__ __attribute__((aligned(16))) unsigned short pb[2][TI][TJP]; // 16.9 KB
    __shared__ float f1s[TI];
    __shared__ float rsw[TI];

    int t = threadIdx.x;
    int i0 = blockIdx.x * TI;
    int b = blockIdx.y;

    int lane = t & 63;
    int w = t >> 6;
    int mrow = lane & 15;
    int quad = lane >> 4;
    int j4 = t & 63;

    if (t < TI) f1s[t] = f1[(size_t)b * NN + i0 + t];
    __syncthreads();

    float f1r[4];
    float ps[4];
#pragma unroll
    for (int m = 0; m < 4; ++m) {
        f1r[m] = f1s[w + 4 * m];
        ps[m] = 0.f;
    }
    f32x4 acc = {0.f, 0.f, 0.f, 0.f};

    const int* adjrow = adj + (((size_t)b * NN + i0) * NN) + 4 * j4;
    const float* f2b = f2 + (size_t)b * NN + 4 * j4;
    const unsigned short* htb =
        ht + (size_t)b * (NN / 32) * (FOUT * 32)
           + (size_t)(w * 16 + mrow) * 32 + 8 * quad;

    // ---- prologue: issue tile 0's loads ----
    int4 avreg[4];
    float4 fv;
#pragma unroll
    for (int m = 0; m < 4; ++m)
        avreg[m] = *(const int4*)(adjrow + (size_t)(w + 4 * m) * NN);
    fv = *(const float4*)f2b;

    for (int jt = 0; jt < NTILE; ++jt) {
        int j0 = jt * TJ;
        unsigned short (*pbc)[TJP] = pb[jt & 1];

        // ---- p-phase: consume avreg/fv (vmcnt wait lands here) ----
        float4 f = fv;
#pragma unroll
        for (int m = 0; m < 4; ++m) {
            int4 av = avreg[m];
            float f1i = f1r[m];
            float4 p;
            p.x = (av.x > 0) ? exp_tanh(f1i + f.x) : 0.f;
            p.y = (av.y > 0) ? exp_tanh(f1i + f.y) : 0.f;
            p.z = (av.z > 0) ? exp_tanh(f1i + f.z) : 0.f;
            p.w = (av.w > 0) ? exp_tanh(f1i + f.w) : 0.f;
            ps[m] += p.x + p.y + p.z + p.w;
            ushort4 pk;
            pk.x = f2bf(p.x); pk.y = f2bf(p.y);
            pk.z = f2bf(p.z); pk.w = f2bf(p.w);
            *(ushort4*)&pbc[w + 4 * m][4 * j4] = pk;
        }

        __syncthreads();   // the ONE barrier: pb[jt&1] visible to all waves
                           // (no vm loads outstanding here -> no drain cost)

        // ---- issue tile jt+1's loads (consumed next iter; crosses NO barrier)
        if (jt + 1 < NTILE) {
#pragma unroll
            for (int m = 0; m < 4; ++m)
                avreg[m] = *(const int4*)(adjrow + (size_t)(w + 4 * m) * NN
                                          + j0 + TJ);
            fv = *(const float4*)(f2b + j0 + TJ);
        }
        __builtin_amdgcn_sched_barrier(0);   // keep issue ahead of PV

        // ---- PV(jt): LDS af + panel-major B + MFMA (hides the issued loads)
        const unsigned short* prow = &pbc[mrow][8 * quad];
        const unsigned short* hpan = htb + (size_t)(j0 >> 5) * (FOUT * 32);
#pragma unroll
        for (int ch = 0; ch < TJ / 32; ++ch) {
            bf16x8 af = *(const bf16x8*)(prow + 32 * ch);
            bf16x8 bf = *(const bf16x8*)(hpan + (size_t)ch * (FOUT * 32));
            acc = __builtin_amdgcn_mfma_f32_16x16x32_bf16(af, bf, acc, 0, 0, 0);
        }
    }

#pragma unroll
    for (int m = 0; m < 4; ++m) {
        float s = ps[m];
#pragma unroll
        for (int off = 32; off > 0; off >>= 1) s += __shfl_down(s, off, 64);
        if (lane == 0) rsw[w + 4 * m] = s;
    }
    __syncthreads();

    float* op = out + ((size_t)b * NN + i0) * FOUT + w * 16 + mrow;
#pragma unroll
    for (int u = 0; u < 4; ++u) {
        int row = quad * 4 + u;
        float rinv = __builtin_amdgcn_rcpf(rsw[row]);
        float sx = acc[u] * rinv;
        op[(size_t)row * FOUT] = (sx > 0.f) ? sx : expm1f(sx);
    }
}

extern "C" void kernel_launch(void* const* d_in, const int* in_sizes, int n_in,
                              void* d_out, int out_size, void* d_ws, size_t ws_size,
                              hipStream_t stream) {
    const float* x   = (const float*)d_in[0];
    const int*   adj = (const int*)d_in[1];
    const float* W   = (const float*)d_in[2];
    const float* a   = (const float*)d_in[3];
    float* out = (float*)d_out;

    unsigned short* ht = (unsigned short*)d_ws;          // 2.1 MB, panel-major
    float* f1   = (float*)(ht + (size_t)BB * FOUT * NN); // B*N
    float* f2   = f1 + (size_t)BB * NN;                  // B*N

    gat_k1<<<dim3(BB * NN / 16), dim3(256), 0, stream>>>(x, W, a, ht, f1, f2);
    gat_k2f<<<dim3(NN / TI, BB), dim3(256), 0, stream>>>(adj, ht, f1, f2, out);
}